// Round 1
// baseline (2217.131 us; speedup 1.0000x reference)
//
#include <hip/hip_runtime.h>
#include <hip/hip_bf16.h>

#define NN 50000
#define EE 800000
#define DD 128

typedef __attribute__((ext_vector_type(8))) short short8;
typedef __attribute__((ext_vector_type(4))) float floatx4;

__device__ __forceinline__ short f2bf(float f) {
  union { float f; unsigned u; } c; c.f = f;
  unsigned r = c.u + 0x7FFFu + ((c.u >> 16) & 1u);  // round-to-nearest-even
  return (short)(r >> 16);
}

// U = A @ Wl^T ; V = A @ Wr^T + bias.  V may alias A (row-private in-place).
// Block: 256 threads = 4 waves; 64 rows per block; each wave does 16 rows x 128 cols.
__global__ __launch_bounds__(256) void dual_gemm(
    const float* __restrict__ A, const float* __restrict__ Wl,
    const float* __restrict__ Wr, const float* __restrict__ bias,
    float* __restrict__ U, float* __restrict__ V)
{
  // bf16 weights in LDS, XOR-swizzled 16B chunks for conflict-free ds_read_b128.
  // Exactly 64 KB total.
  __shared__ __align__(16) short lw[2][DD * DD];
  int t = threadIdx.x;
  for (int i = t; i < DD * DD; i += 256) {
    int r = i >> 7, c = i & 127;
    int idx = r * DD + (((c >> 3) ^ (r & 15)) << 3) + (c & 7);
    lw[0][idx] = f2bf(Wl[i]);
    lw[1][idx] = f2bf(Wr[i]);
  }

  int wave = t >> 6, lane = t & 63;
  int m = lane & 15, q = lane >> 4;
  int row_tile = blockIdx.x * 64 + wave * 16 + m;   // A row this lane loads
  int ar = row_tile < NN ? row_tile : NN - 1;       // clamp (masked on store)

  // A fragments held in registers across whole column loop: k = kc*32 + q*8 + j
  short8 af[4];
  const floatx4* ap = (const floatx4*)(A + (size_t)ar * DD);
#pragma unroll
  for (int kc = 0; kc < 4; ++kc) {
    floatx4 p0 = ap[kc * 8 + q * 2];
    floatx4 p1 = ap[kc * 8 + q * 2 + 1];
    short8 s;
    s[0] = f2bf(p0[0]); s[1] = f2bf(p0[1]); s[2] = f2bf(p0[2]); s[3] = f2bf(p0[3]);
    s[4] = f2bf(p1[0]); s[5] = f2bf(p1[1]); s[6] = f2bf(p1[2]); s[7] = f2bf(p1[3]);
    af[kc] = s;
  }
  __syncthreads();

  int r0 = blockIdx.x * 64 + wave * 16 + q * 4;     // C row base for this lane
#pragma unroll
  for (int ct = 0; ct < 8; ++ct) {
    floatx4 au = {0.f, 0.f, 0.f, 0.f}, av = {0.f, 0.f, 0.f, 0.f};
    int col = ct * 16 + m;                          // output col == weight row
    const short* pl = &lw[0][col * DD];
    const short* pr = &lw[1][col * DD];
#pragma unroll
    for (int kc = 0; kc < 4; ++kc) {
      int pos = (((kc * 4 + q) ^ m) << 3);
      short8 bl_ = *(const short8*)(pl + pos);
      short8 br_ = *(const short8*)(pr + pos);
      au = __builtin_amdgcn_mfma_f32_16x16x32_bf16(af[kc], bl_, au, 0, 0, 0);
      av = __builtin_amdgcn_mfma_f32_16x16x32_bf16(af[kc], br_, av, 0, 0, 0);
    }
    float bv = bias[col];
#pragma unroll
    for (int r = 0; r < 4; ++r) {
      int row = r0 + r;
      if (row < NN) {
        U[(size_t)row * DD + col] = au[r];
        V[(size_t)row * DD + col] = av[r] + bv;
      }
    }
  }
}

// V[dst[e]] += U[src[e]]  — one wave per edge, float2 per lane.
__global__ __launch_bounds__(256) void scatter_add(
    const float* __restrict__ U, const int* __restrict__ src,
    const int* __restrict__ dst, float* __restrict__ V)
{
  int e = blockIdx.x * 4 + (threadIdx.x >> 6);
  int lane = threadIdx.x & 63;
  int s = src[e];
  int d = dst[e];
  float2 val = ((const float2*)(U + (size_t)s * DD))[lane];
  float* vp = V + (size_t)d * DD + lane * 2;
  unsafeAtomicAdd(vp, val.x);
  unsafeAtomicAdd(vp + 1, val.y);
}

// In-place LayerNorm (over 128) + ReLU — one wave per row.
__global__ __launch_bounds__(256) void ln_relu(
    float* __restrict__ H, const float* __restrict__ g, const float* __restrict__ b)
{
  int row = blockIdx.x * 4 + (threadIdx.x >> 6);
  if (row >= NN) return;
  int lane = threadIdx.x & 63;
  float2* hp = (float2*)(H + (size_t)row * DD);
  float2 v = hp[lane];
  float s = v.x + v.y;
#pragma unroll
  for (int off = 32; off >= 1; off >>= 1) s += __shfl_xor(s, off, 64);
  float mu = s * (1.0f / 128.0f);
  float dx = v.x - mu, dy = v.y - mu;
  float qv = dx * dx + dy * dy;
#pragma unroll
  for (int off = 32; off >= 1; off >>= 1) qv += __shfl_xor(qv, off, 64);
  float rstd = rsqrtf(qv * (1.0f / 128.0f) + 1e-5f);
  float2 gg = ((const float2*)g)[lane];
  float2 bb = ((const float2*)b)[lane];
  float o0 = dx * rstd * gg.x + bb.x;
  float o1 = dy * rstd * gg.y + bb.y;
  v.x = o0 > 0.f ? o0 : 0.f;
  v.y = o1 > 0.f ? o1 : 0.f;
  hp[lane] = v;
}

__global__ __launch_bounds__(256) void relu_k(float* __restrict__ H, int n4)
{
  int i = blockIdx.x * 256 + threadIdx.x;
  if (i >= n4) return;
  floatx4* p = (floatx4*)H;
  floatx4 v = p[i];
  v[0] = fmaxf(v[0], 0.f);
  v[1] = fmaxf(v[1], 0.f);
  v[2] = fmaxf(v[2], 0.f);
  v[3] = fmaxf(v[3], 0.f);
  p[i] = v;
}

extern "C" void kernel_launch(void* const* d_in, const int* in_sizes, int n_in,
                              void* d_out, int out_size, void* d_ws, size_t ws_size,
                              hipStream_t stream) {
  const float* x   = (const float*)d_in[0];
  const int*   ei  = (const int*)d_in[1];
  const int* src = ei;            // edge_index[0]
  const int* dst = ei + EE;       // edge_index[1]
  const float* Wl0 = (const float*)d_in[2];
  const float* bl0 = (const float*)d_in[3];
  const float* Wr0 = (const float*)d_in[4];
  const float* Wl1 = (const float*)d_in[5];
  const float* bl1 = (const float*)d_in[6];
  const float* Wr1 = (const float*)d_in[7];
  const float* Wl2 = (const float*)d_in[8];
  const float* bl2 = (const float*)d_in[9];
  const float* Wr2 = (const float*)d_in[10];
  const float* lng = (const float*)d_in[11];
  const float* lnb = (const float*)d_in[12];

  float* out = (float*)d_out;     // doubles as V / h buffer every layer
  float* U   = (float*)d_ws;      // N*D floats = 25.6 MB scratch

  dim3 blk(256);
  int ggrid = (NN + 63) / 64;     // 782

  // layer 0: conv -> LN -> ReLU
  dual_gemm<<<ggrid, blk, 0, stream>>>(x, Wl0, Wr0, bl0, U, out);
  scatter_add<<<EE / 4, blk, 0, stream>>>(U, src, dst, out);
  ln_relu<<<NN / 4, blk, 0, stream>>>(out, lng, lnb);

  // layer 1: conv -> ReLU   (dual_gemm reads `out` and writes V in-place over it)
  dual_gemm<<<ggrid, blk, 0, stream>>>(out, Wl1, Wr1, bl1, U, out);
  scatter_add<<<EE / 4, blk, 0, stream>>>(U, src, dst, out);
  relu_k<<<NN * DD / 4 / 256, blk, 0, stream>>>(out, NN * DD / 4);

  // layer 2: final conv, no activation
  dual_gemm<<<ggrid, blk, 0, stream>>>(out, Wl2, Wr2, bl2, U, out);
  scatter_add<<<EE / 4, blk, 0, stream>>>(U, src, dst, out);
}

// Round 2
// 451.363 us; speedup vs baseline: 4.9121x; 4.9121x over previous
//
#include <hip/hip_runtime.h>
#include <hip/hip_bf16.h>

#define NN 50000
#define EE 800000
#define DD 128

typedef __attribute__((ext_vector_type(8))) short short8;
typedef __attribute__((ext_vector_type(4))) float floatx4;

__device__ __forceinline__ short f2bf(float f) {
  union { float f; unsigned u; } c; c.f = f;
  unsigned r = c.u + 0x7FFFu + ((c.u >> 16) & 1u);  // round-to-nearest-even
  return (short)(r >> 16);
}

// ---------------- CSR build (edges identical for all 3 layers) ----------------

__global__ __launch_bounds__(256) void zero_ints(int* __restrict__ p, int n) {
  int i = blockIdx.x * 256 + threadIdx.x;
  if (i < n) p[i] = 0;
}

__global__ __launch_bounds__(256) void hist(const int* __restrict__ dst, int* __restrict__ deg) {
  int e = blockIdx.x * 256 + threadIdx.x;
  if (e < EE) atomicAdd(&deg[dst[e]], 1);
}

// Segment order is irrelevant -> atomic cursor instead of a prefix-sum.
__global__ __launch_bounds__(256) void assign_start(const int* __restrict__ deg,
                                                    int* __restrict__ start,
                                                    int* __restrict__ cursor) {
  int n = blockIdx.x * 256 + threadIdx.x;
  if (n < NN) start[n] = atomicAdd(cursor, deg[n]);
}

__global__ __launch_bounds__(256) void place(const int* __restrict__ src,
                                             const int* __restrict__ dst,
                                             const int* __restrict__ start,
                                             int* __restrict__ fill,
                                             int* __restrict__ srcSorted) {
  int e = blockIdx.x * 256 + threadIdx.x;
  if (e < EE) {
    int d = dst[e];
    int p = start[d] + atomicAdd(&fill[d], 1);
    srcSorted[p] = src[e];
  }
}

// ---------- one-time weight conversion: fp32 -> bf16, LDS-swizzled layout ----------
// Wbf layout: [mat 0..5][r*128 + swz(c,r)] where mats are {Wl0,Wr0,Wl1,Wr1,Wl2,Wr2}.
__global__ __launch_bounds__(256) void prep_weights(
    const float* __restrict__ W0, const float* __restrict__ W1,
    const float* __restrict__ W2, const float* __restrict__ W3,
    const float* __restrict__ W4, const float* __restrict__ W5,
    short* __restrict__ Wbf) {
  int i = blockIdx.x * 256 + threadIdx.x;       // 0..98303
  int mat = i >> 14, local = i & 16383;
  const float* W;
  switch (mat) {
    case 0: W = W0; break;
    case 1: W = W1; break;
    case 2: W = W2; break;
    case 3: W = W3; break;
    case 4: W = W4; break;
    default: W = W5; break;
  }
  int r = local >> 7, c = local & 127;
  int idx = r * DD + (((c >> 3) ^ (r & 15)) << 3) + (c & 7);
  Wbf[(mat << 14) + idx] = f2bf(W[local]);
}

// ---------------- dual GEMM: U = A@Wl^T ; V = A@Wr^T + bias ----------------
// Wpair: pre-swizzled bf16 [Wl | Wr], 2*16384 shorts. V may alias A (row-private).
__global__ __launch_bounds__(256) void dual_gemm(
    const float* __restrict__ A, const short* __restrict__ Wpair,
    const float* __restrict__ bias,
    float* __restrict__ U, float* __restrict__ V)
{
  __shared__ __align__(16) short lw[2 * DD * DD];   // 64 KB
  int t = threadIdx.x;
  {
    const short8* gp = (const short8*)Wpair;
    short8* lp = (short8*)lw;
#pragma unroll
    for (int i = 0; i < 16; ++i) lp[t + i * 256] = gp[t + i * 256];
  }

  int wave = t >> 6, lane = t & 63;
  int m = lane & 15, q = lane >> 4;
  int row_tile = blockIdx.x * 64 + wave * 16 + m;   // A row this lane loads
  int ar = row_tile < NN ? row_tile : NN - 1;       // clamp (masked on store)

  // A fragments in registers across whole column loop: k = kc*32 + q*8 + j
  short8 af[4];
  const floatx4* ap = (const floatx4*)(A + (size_t)ar * DD);
#pragma unroll
  for (int kc = 0; kc < 4; ++kc) {
    floatx4 p0 = ap[kc * 8 + q * 2];
    floatx4 p1 = ap[kc * 8 + q * 2 + 1];
    short8 s;
    s[0] = f2bf(p0[0]); s[1] = f2bf(p0[1]); s[2] = f2bf(p0[2]); s[3] = f2bf(p0[3]);
    s[4] = f2bf(p1[0]); s[5] = f2bf(p1[1]); s[6] = f2bf(p1[2]); s[7] = f2bf(p1[3]);
    af[kc] = s;
  }
  __syncthreads();

  int r0 = blockIdx.x * 64 + wave * 16 + q * 4;     // C row base for this lane
#pragma unroll
  for (int ct = 0; ct < 8; ++ct) {
    floatx4 au = {0.f, 0.f, 0.f, 0.f}, av = {0.f, 0.f, 0.f, 0.f};
    int col = ct * 16 + m;                          // output col == weight row
    const short* pl = &lw[col * DD];
    const short* pr = &lw[DD * DD + col * DD];
#pragma unroll
    for (int kc = 0; kc < 4; ++kc) {
      int pos = (((kc * 4 + q) ^ m) << 3);
      short8 bl_ = *(const short8*)(pl + pos);
      short8 br_ = *(const short8*)(pr + pos);
      au = __builtin_amdgcn_mfma_f32_16x16x32_bf16(af[kc], bl_, au, 0, 0, 0);
      av = __builtin_amdgcn_mfma_f32_16x16x32_bf16(af[kc], br_, av, 0, 0, 0);
    }
    float bv = bias[col];
#pragma unroll
    for (int r = 0; r < 4; ++r) {
      int row = r0 + r;
      if (row < NN) {
        U[(size_t)row * DD + col] = au[r];
        V[(size_t)row * DD + col] = av[r] + bv;
      }
    }
  }
}

// ---------------- fused aggregate (+ LN/ReLU epilogue) ----------------
// One wave per node: H[n] = V[n] + sum_{e: dst=n} U[srcSorted[e]], then epilogue.
// MODE 0: LayerNorm+ReLU; MODE 1: ReLU; MODE 2: none.
template <int MODE>
__global__ __launch_bounds__(256) void agg_fuse(
    const float* __restrict__ U, const int* __restrict__ srcSorted,
    const int* __restrict__ start, const int* __restrict__ deg,
    float* __restrict__ H, const float* __restrict__ g, const float* __restrict__ b)
{
  int node = blockIdx.x * 4 + (threadIdx.x >> 6);
  if (node >= NN) return;
  int lane = threadIdx.x & 63;
  int s0 = start[node];
  int dg = deg[node];
  float2* hp = (float2*)(H + (size_t)node * DD);
  float2 acc = hp[lane];                       // root path: x@Wr^T + b

  int i = 0;
  for (; i + 1 < dg; i += 2) {
    int sa = srcSorted[s0 + i];
    int sb = srcSorted[s0 + i + 1];
    float2 va = ((const float2*)(U + (size_t)sa * DD))[lane];
    float2 vb = ((const float2*)(U + (size_t)sb * DD))[lane];
    acc.x += va.x + vb.x;
    acc.y += va.y + vb.y;
  }
  if (i < dg) {
    int sa = srcSorted[s0 + i];
    float2 va = ((const float2*)(U + (size_t)sa * DD))[lane];
    acc.x += va.x;
    acc.y += va.y;
  }

  if (MODE == 0) {
    float s = acc.x + acc.y;
#pragma unroll
    for (int off = 32; off >= 1; off >>= 1) s += __shfl_xor(s, off, 64);
    float mu = s * (1.0f / 128.0f);
    float dx = acc.x - mu, dy = acc.y - mu;
    float qv = dx * dx + dy * dy;
#pragma unroll
    for (int off = 32; off >= 1; off >>= 1) qv += __shfl_xor(qv, off, 64);
    float rstd = rsqrtf(qv * (1.0f / 128.0f) + 1e-5f);
    float2 gg = ((const float2*)g)[lane];
    float2 bb = ((const float2*)b)[lane];
    float o0 = dx * rstd * gg.x + bb.x;
    float o1 = dy * rstd * gg.y + bb.y;
    acc.x = o0 > 0.f ? o0 : 0.f;
    acc.y = o1 > 0.f ? o1 : 0.f;
  } else if (MODE == 1) {
    acc.x = acc.x > 0.f ? acc.x : 0.f;
    acc.y = acc.y > 0.f ? acc.y : 0.f;
  }
  hp[lane] = acc;
}

// ---------------- launch ----------------

extern "C" void kernel_launch(void* const* d_in, const int* in_sizes, int n_in,
                              void* d_out, int out_size, void* d_ws, size_t ws_size,
                              hipStream_t stream) {
  const float* x   = (const float*)d_in[0];
  const int*   ei  = (const int*)d_in[1];
  const int* src = ei;            // edge_index[0]
  const int* dst = ei + EE;       // edge_index[1]
  const float* Wl0 = (const float*)d_in[2];
  const float* bl0 = (const float*)d_in[3];
  const float* Wr0 = (const float*)d_in[4];
  const float* Wl1 = (const float*)d_in[5];
  const float* bl1 = (const float*)d_in[6];
  const float* Wr1 = (const float*)d_in[7];
  const float* Wl2 = (const float*)d_in[8];
  const float* bl2 = (const float*)d_in[9];
  const float* Wr2 = (const float*)d_in[10];
  const float* lng = (const float*)d_in[11];
  const float* lnb = (const float*)d_in[12];

  float* out = (float*)d_out;                 // V / h buffer every layer

  // workspace layout
  float* U = (float*)d_ws;                    // NN*DD floats = 25.6 MB
  short* Wbf = (short*)(U + (size_t)NN * DD); // 6*16384 shorts
  int* srcSorted = (int*)(Wbf + 6 * DD * DD); // EE ints
  int* deg    = srcSorted + EE;               // NN
  int* start  = deg + NN;                     // NN
  int* fill   = start + NN;                   // NN
  int* cursor = fill + NN;                    // 1
  // total ~29.6 MB

  dim3 blk(256);

  // CSR build + weight prep (once; reused by all 3 layers)
  zero_ints<<<(3 * NN + 1 + 255) / 256, blk, 0, stream>>>(deg, 3 * NN + 1);
  prep_weights<<<6 * DD * DD / 256, blk, 0, stream>>>(Wl0, Wr0, Wl1, Wr1, Wl2, Wr2, Wbf);
  hist<<<EE / 256, blk, 0, stream>>>(dst, deg);
  assign_start<<<(NN + 255) / 256, blk, 0, stream>>>(deg, start, cursor);
  place<<<EE / 256, blk, 0, stream>>>(src, dst, start, fill, srcSorted);

  int ggrid = (NN + 63) / 64;     // 782
  int agrid = (NN + 3) / 4;       // 12500

  // layer 0: conv -> LN -> ReLU (fused)
  dual_gemm<<<ggrid, blk, 0, stream>>>(x, Wbf + 0 * 2 * DD * DD, bl0, U, out);
  agg_fuse<0><<<agrid, blk, 0, stream>>>(U, srcSorted, start, deg, out, lng, lnb);

  // layer 1: conv -> ReLU (fused)
  dual_gemm<<<ggrid, blk, 0, stream>>>(out, Wbf + 1 * 2 * DD * DD, bl1, U, out);
  agg_fuse<1><<<agrid, blk, 0, stream>>>(U, srcSorted, start, deg, out, lng, lnb);

  // layer 2: final conv, no activation
  dual_gemm<<<ggrid, blk, 0, stream>>>(out, Wbf + 2 * 2 * DD * DD, bl2, U, out);
  agg_fuse<2><<<agrid, blk, 0, stream>>>(U, srcSorted, start, deg, out, lng, lnb);
}

// Round 3
// 352.358 us; speedup vs baseline: 6.2923x; 1.2810x over previous
//
#include <hip/hip_runtime.h>
#include <hip/hip_bf16.h>

#define NN 50000
#define EE 800000
#define DD 128
#define CAP (EE + 3 * NN + 64)   // padded srcSorted capacity

typedef __attribute__((ext_vector_type(8))) short short8;
typedef __attribute__((ext_vector_type(4))) float floatx4;

__device__ __forceinline__ short f2bf(float f) {
  union { float f; unsigned u; } c; c.f = f;
  unsigned r = c.u + 0x7FFFu + ((c.u >> 16) & 1u);  // round-to-nearest-even
  return (short)(r >> 16);
}
__device__ __forceinline__ float bf2f(short s) {
  union { unsigned u; float f; } c; c.u = ((unsigned)(unsigned short)s) << 16;
  return c.f;
}

// ---------------- CSR build (edges identical for all 3 layers) ----------------

__global__ __launch_bounds__(256) void zero_ints(int* __restrict__ p, int n) {
  int i = blockIdx.x * 256 + threadIdx.x;
  if (i < n) p[i] = 0;
}

__global__ __launch_bounds__(256) void fill_dummy(int* __restrict__ p, int n) {
  int i = blockIdx.x * 256 + threadIdx.x;
  if (i < n) p[i] = NN;            // dummy src -> zero row of Ubf
}

__global__ __launch_bounds__(256) void hist(const int* __restrict__ dst, int* __restrict__ deg) {
  int e = blockIdx.x * 256 + threadIdx.x;
  if (e < EE) atomicAdd(&deg[dst[e]], 1);
}

// Segments padded to multiple of 4; order irrelevant -> atomic cursor.
__global__ __launch_bounds__(256) void assign_start(const int* __restrict__ deg,
                                                    int* __restrict__ start,
                                                    int* __restrict__ cursor) {
  int n = blockIdx.x * 256 + threadIdx.x;
  if (n < NN) start[n] = atomicAdd(cursor, (deg[n] + 3) & ~3);
}

__global__ __launch_bounds__(256) void place(const int* __restrict__ src,
                                             const int* __restrict__ dst,
                                             const int* __restrict__ start,
                                             int* __restrict__ fill,
                                             int* __restrict__ srcSorted) {
  int e = blockIdx.x * 256 + threadIdx.x;
  if (e < EE) {
    int d = dst[e];
    int p = start[d] + atomicAdd(&fill[d], 1);
    srcSorted[p] = src[e];
  }
}

// ---------- one-time weight conversion: fp32 -> bf16, LDS-swizzled layout ----------
__global__ __launch_bounds__(256) void prep_weights(
    const float* __restrict__ W0, const float* __restrict__ W1,
    const float* __restrict__ W2, const float* __restrict__ W3,
    const float* __restrict__ W4, const float* __restrict__ W5,
    short* __restrict__ Wbf, short* __restrict__ UbfZeroRow) {
  if (blockIdx.x == 0 && threadIdx.x < 64)
    ((int*)UbfZeroRow)[threadIdx.x] = 0;       // zero the dummy row NN
  int i = blockIdx.x * 256 + threadIdx.x;      // 0..98303
  int mat = i >> 14, local = i & 16383;
  const float* W;
  switch (mat) {
    case 0: W = W0; break;
    case 1: W = W1; break;
    case 2: W = W2; break;
    case 3: W = W3; break;
    case 4: W = W4; break;
    default: W = W5; break;
  }
  int r = local >> 7, c = local & 127;
  int idx = r * DD + (((c >> 3) ^ (r & 15)) << 3) + (c & 7);
  Wbf[(mat << 14) + idx] = f2bf(W[local]);
}

// ---------------- dual GEMM: U = A@Wl^T (bf16 out); V = A@Wr^T + bias (fp32) ----------------
template <int BF16IN>
__global__ __launch_bounds__(256) void dual_gemm(
    const void* __restrict__ Ain, const short* __restrict__ Wpair,
    const float* __restrict__ bias,
    short* __restrict__ Ubf, float* __restrict__ V)
{
  __shared__ __align__(16) short lw[2 * DD * DD];   // 64 KB
  int t = threadIdx.x;
  {
    const short8* gp = (const short8*)Wpair;
    short8* lp = (short8*)lw;
#pragma unroll
    for (int i = 0; i < 16; ++i) lp[t + i * 256] = gp[t + i * 256];
  }

  int wave = t >> 6, lane = t & 63;
  int m = lane & 15, q = lane >> 4;
  int row_tile = blockIdx.x * 64 + wave * 16 + m;
  int ar = row_tile < NN ? row_tile : NN - 1;       // clamp (masked on store)

  short8 af[4];                                     // k = kc*32 + q*8 + j
  if (BF16IN) {
    const short8* ap = (const short8*)((const short*)Ain + (size_t)ar * DD);
#pragma unroll
    for (int kc = 0; kc < 4; ++kc) af[kc] = ap[kc * 4 + q];
  } else {
    const floatx4* ap = (const floatx4*)((const float*)Ain + (size_t)ar * DD);
#pragma unroll
    for (int kc = 0; kc < 4; ++kc) {
      floatx4 p0 = ap[kc * 8 + q * 2];
      floatx4 p1 = ap[kc * 8 + q * 2 + 1];
      short8 s;
      s[0] = f2bf(p0[0]); s[1] = f2bf(p0[1]); s[2] = f2bf(p0[2]); s[3] = f2bf(p0[3]);
      s[4] = f2bf(p1[0]); s[5] = f2bf(p1[1]); s[6] = f2bf(p1[2]); s[7] = f2bf(p1[3]);
      af[kc] = s;
    }
  }
  __syncthreads();

  int r0 = blockIdx.x * 64 + wave * 16 + q * 4;
#pragma unroll
  for (int ct = 0; ct < 8; ++ct) {
    floatx4 au = {0.f, 0.f, 0.f, 0.f}, av = {0.f, 0.f, 0.f, 0.f};
    int col = ct * 16 + m;
    const short* pl = &lw[col * DD];
    const short* pr = &lw[DD * DD + col * DD];
#pragma unroll
    for (int kc = 0; kc < 4; ++kc) {
      int pos = (((kc * 4 + q) ^ m) << 3);
      short8 bl_ = *(const short8*)(pl + pos);
      short8 br_ = *(const short8*)(pr + pos);
      au = __builtin_amdgcn_mfma_f32_16x16x32_bf16(af[kc], bl_, au, 0, 0, 0);
      av = __builtin_amdgcn_mfma_f32_16x16x32_bf16(af[kc], br_, av, 0, 0, 0);
    }
    float bv = bias[col];
#pragma unroll
    for (int r = 0; r < 4; ++r) {
      int row = r0 + r;
      if (row < NN) {
        Ubf[(size_t)row * DD + col] = f2bf(au[r]);
        V[(size_t)row * DD + col] = av[r] + bv;
      }
    }
  }
}

// ---------------- fused aggregate (+ LN/ReLU epilogue) ----------------
// One wave per node, 4 edges/iter: lane (c=lane&15, r=lane>>4) gathers 16B of
// row srcSorted[s0+4*it+r]; shfl fold merges the 4 row-slots at the end.
// MODE 0: LayerNorm+ReLU; 1: ReLU; 2: none.  BF16OUT: h stored bf16 vs fp32.
template <int MODE, int BF16OUT>
__global__ __launch_bounds__(256) void agg_fuse(
    const short* __restrict__ Ubf, const int* __restrict__ srcSorted,
    const int* __restrict__ start, const int* __restrict__ deg,
    const float* __restrict__ V, void* __restrict__ H,
    const float* __restrict__ g, const float* __restrict__ b)
{
  int node = blockIdx.x * 4 + (threadIdx.x >> 6);
  if (node >= NN) return;
  int lane = threadIdx.x & 63;
  int c = lane & 15, r = lane >> 4;
  int s0 = start[node];
  int niter = (deg[node] + 3) >> 2;

  float acc[8] = {0.f, 0.f, 0.f, 0.f, 0.f, 0.f, 0.f, 0.f};
  const int* ip = srcSorted + s0 + r;
  const size_t coff = (size_t)(c << 3);

  int it = 0;
  for (; it + 2 <= niter; it += 2) {
    int ra = ip[it * 4];
    int rb = ip[it * 4 + 4];
    short8 va = *(const short8*)(Ubf + ((size_t)ra << 7) + coff);
    short8 vb = *(const short8*)(Ubf + ((size_t)rb << 7) + coff);
#pragma unroll
    for (int j = 0; j < 8; ++j) acc[j] += bf2f(va[j]) + bf2f(vb[j]);
  }
  if (it < niter) {
    int ra = ip[it * 4];
    short8 va = *(const short8*)(Ubf + ((size_t)ra << 7) + coff);
#pragma unroll
    for (int j = 0; j < 8; ++j) acc[j] += bf2f(va[j]);
  }

  // fold the 4 row-slots: acc[j] becomes full neighbor-sum for col c*8+j
#pragma unroll
  for (int j = 0; j < 8; ++j) {
    acc[j] += __shfl_xor(acc[j], 16, 64);
    acc[j] += __shfl_xor(acc[j], 32, 64);
  }

  int colbase = (c << 3) + (r << 1);    // this lane's 2 output cols
  float o0, o1;
  if (MODE == 0) {
    // add full root-path chunk so LN stats see h = V + agg
    const floatx4* vp = (const floatx4*)(V + (size_t)node * DD + (c << 3));
    floatx4 v0 = vp[0], v1 = vp[1];
#pragma unroll
    for (int j = 0; j < 4; ++j) { acc[j] += v0[j]; acc[4 + j] += v1[j]; }
    float s = 0.f;
#pragma unroll
    for (int j = 0; j < 8; ++j) s += acc[j];
#pragma unroll
    for (int off = 8; off >= 1; off >>= 1) s += __shfl_xor(s, off, 64);
    float mu = s * (1.0f / 128.0f);
    float q2 = 0.f;
#pragma unroll
    for (int j = 0; j < 8; ++j) { float d = acc[j] - mu; q2 += d * d; }
#pragma unroll
    for (int off = 8; off >= 1; off >>= 1) q2 += __shfl_xor(q2, off, 64);
    float rstd = rsqrtf(q2 * (1.0f / 128.0f) + 1e-5f);
    float2 gg = *(const float2*)(g + colbase);
    float2 bb = *(const float2*)(b + colbase);
    o0 = (acc[(r << 1)] - mu) * rstd * gg.x + bb.x;
    o1 = (acc[(r << 1) + 1] - mu) * rstd * gg.y + bb.y;
    o0 = o0 > 0.f ? o0 : 0.f;
    o1 = o1 > 0.f ? o1 : 0.f;
  } else {
    float2 vv = *(const float2*)(V + (size_t)node * DD + colbase);
    o0 = acc[(r << 1)] + vv.x;
    o1 = acc[(r << 1) + 1] + vv.y;
    if (MODE == 1) {
      o0 = o0 > 0.f ? o0 : 0.f;
      o1 = o1 > 0.f ? o1 : 0.f;
    }
  }

  if (BF16OUT) {
    unsigned pack = ((unsigned)(unsigned short)f2bf(o0)) |
                    (((unsigned)(unsigned short)f2bf(o1)) << 16);
    ((unsigned*)H)[((size_t)node * DD + colbase) >> 1] = pack;
  } else {
    float2 o = {o0, o1};
    *(float2*)((float*)H + (size_t)node * DD + colbase) = o;
  }
}

// ---------------- launch ----------------

extern "C" void kernel_launch(void* const* d_in, const int* in_sizes, int n_in,
                              void* d_out, int out_size, void* d_ws, size_t ws_size,
                              hipStream_t stream) {
  const float* x   = (const float*)d_in[0];
  const int*   ei  = (const int*)d_in[1];
  const int* src = ei;            // edge_index[0]
  const int* dst = ei + EE;       // edge_index[1]
  const float* Wl0 = (const float*)d_in[2];
  const float* bl0 = (const float*)d_in[3];
  const float* Wr0 = (const float*)d_in[4];
  const float* Wl1 = (const float*)d_in[5];
  const float* bl1 = (const float*)d_in[6];
  const float* Wr1 = (const float*)d_in[7];
  const float* Wl2 = (const float*)d_in[8];
  const float* bl2 = (const float*)d_in[9];
  const float* Wr2 = (const float*)d_in[10];
  const float* lng = (const float*)d_in[11];
  const float* lnb = (const float*)d_in[12];

  float* outF = (float*)d_out;                    // V scratch every layer; final h

  // workspace layout (16B-aligned chunks)
  short* Ubf = (short*)d_ws;                      // (NN+1)*DD bf16 = 12.8 MB
  short* Wbf = Ubf + (size_t)(NN + 1) * DD;       // 6*16384 shorts
  short* Hbf = Wbf + 6 * DD * DD;                 // NN*DD bf16 = 12.8 MB
  int* srcSorted = (int*)(Hbf + (size_t)NN * DD); // CAP ints
  int* deg    = srcSorted + CAP;                  // NN
  int* start  = deg + NN;                         // NN
  int* fill   = start + NN;                       // NN
  int* cursor = fill + NN;                        // 1  (zeroed via 3*NN+1 span)

  dim3 blk(256);

  // CSR build + weight prep (once; reused by all 3 layers)
  zero_ints<<<(3 * NN + 1 + 255) / 256, blk, 0, stream>>>(deg, 3 * NN + 1);
  fill_dummy<<<(CAP + 255) / 256, blk, 0, stream>>>(srcSorted, CAP);
  prep_weights<<<6 * DD * DD / 256, blk, 0, stream>>>(Wl0, Wr0, Wl1, Wr1, Wl2, Wr2,
                                                      Wbf, Ubf + (size_t)NN * DD);
  hist<<<EE / 256, blk, 0, stream>>>(dst, deg);
  assign_start<<<(NN + 255) / 256, blk, 0, stream>>>(deg, start, cursor);
  place<<<EE / 256, blk, 0, stream>>>(src, dst, start, fill, srcSorted);

  int ggrid = (NN + 63) / 64;     // 782
  int agrid = (NN + 3) / 4;       // 12500

  // layer 0: conv -> LN -> ReLU (fused), h -> bf16
  dual_gemm<0><<<ggrid, blk, 0, stream>>>(x, Wbf + 0 * 2 * DD * DD, bl0, Ubf, outF);
  agg_fuse<0, 1><<<agrid, blk, 0, stream>>>(Ubf, srcSorted, start, deg, outF, Hbf, lng, lnb);

  // layer 1: conv -> ReLU (fused), h -> bf16
  dual_gemm<1><<<ggrid, blk, 0, stream>>>(Hbf, Wbf + 1 * 2 * DD * DD, bl1, Ubf, outF);
  agg_fuse<1, 1><<<agrid, blk, 0, stream>>>(Ubf, srcSorted, start, deg, outF, Hbf, lng, lnb);

  // layer 2: final conv, no activation, h -> fp32 d_out (in-place over V)
  dual_gemm<1><<<ggrid, blk, 0, stream>>>(Hbf, Wbf + 2 * 2 * DD * DD, bl2, Ubf, outF);
  agg_fuse<2, 0><<<agrid, blk, 0, stream>>>(Ubf, srcSorted, start, deg, outF, outF, lng, lnb);
}